// Round 13
// baseline (409.794 us; speedup 1.0000x reference)
//
#include <hip/hip_runtime.h>
#include <hip/hip_bf16.h>

typedef unsigned short u16;
typedef unsigned int u32;
typedef _Float16 f16;
typedef __attribute__((ext_vector_type(4))) float f32x4;
typedef __attribute__((ext_vector_type(4))) _Float16 f16x4;
typedef __attribute__((ext_vector_type(8))) _Float16 f16x8;

__device__ __forceinline__ void gll16(const void* g, void* l) {
    __builtin_amdgcn_global_load_lds(
        (const __attribute__((address_space(1))) void*)g,
        (__attribute__((address_space(3))) void*)l, 16, 0, 0);
}

// fast exp2: v_exp_f32 computes 2^x directly (ISA §3). Pure op -> non-volatile
// asm so the scheduler can interleave the 16 independent calls.
__device__ __forceinline__ float fexp2(float x) {
    float r;
    asm("v_exp_f32 %0, %1" : "=v"(r) : "v"(x));
    return r;
}

// ---------------- prep kernels ----------------

__global__ __launch_bounds__(256) void cast_x_kernel(
    const float* __restrict__ x, f16* __restrict__ xf) {
    int i = blockIdx.x * 256 + threadIdx.x;       // < 1048576 (float4 count)
    float4 v = ((const float4*)x)[i];
    f16x4 o;
    o[0] = (f16)v.x; o[1] = (f16)v.y; o[2] = (f16)v.z; o[3] = (f16)v.w;
    ((f16x4*)xf)[i] = o;
}

// transpose + cast the 4 weight matrices into [N][K] fp16 layout
__global__ __launch_bounds__(256) void cast_wT_kernel(
    const float* __restrict__ Wq1, const float* __restrict__ Wk1,
    const float* __restrict__ Wq2, const float* __restrict__ Wk2,
    f16* __restrict__ w1f, f16* __restrict__ w2f) {
    int y = blockIdx.y;
    const float* src = (y == 0) ? Wq1 : (y == 1) ? Wk1 : (y == 2) ? Wq2 : Wk2;
    int R = (y < 2) ? 256 : 512;   // src rows = K of GEMM
    int C = (y < 2) ? 512 : 256;   // src cols = N of GEMM
    f16* d = ((y < 2) ? w1f : w2f) + (y & 1) * 131072;
    int i = blockIdx.x * 256 + threadIdx.x;       // < 131072
    int c = i / R, r = i - c * R;                 // out[c][r] = src[r][c]
    d[i] = (f16)src[(size_t)r * C + c];
}

__global__ void pack_bias(const float* __restrict__ bq1, const float* __restrict__ bk1,
                          const float* __restrict__ bq2, const float* __restrict__ bk2,
                          float* __restrict__ b1, float* __restrict__ b2) {
    int t = threadIdx.x;                           // 512 threads
    b1[t] = bq1[t]; b1[512 + t] = bk1[t];
    if (t < 256) { b2[t] = bq2[t]; b2[256 + t] = bk2[t]; }
}

// ---------------- fp16 GEMM: C[M,N] = A[M,K] * B[N,K]^T ----------------
// (unchanged from r11 -- measurement round for softmax/branch hypotheses)
#define BM 128
#define BN 128
#define BKT 32

template<int BIAS, int RELU, int OUTMODE>
__global__ __launch_bounds__(256, 2)
void gemm_bt(const f16* __restrict__ A, const f16* __restrict__ B,
             const float* __restrict__ bias, long biasBatch,
             u16* __restrict__ C1,
             int M, int N, int K,
             long aBatch, long bBatch, long cBatch) {
    constexpr int TILEU = BM * BKT;          // 4096 f16 = 8KB per matrix-tile
    constexpr int HALFU = 2 * TILEU;         // A|B per buffer
    __shared__ u16 lds[2 * HALFU];           // 32KB double-buffered

    const int tid = threadIdx.x;
    const int wave = tid >> 6, lane = tid & 63;

    // bijective XCD-aware block swizzle (T1/m204)
    u32 gx = gridDim.x, gy = gridDim.y, gz = gridDim.z;
    u32 flat = (blockIdx.z * gy + blockIdx.y) * gx + blockIdx.x;
    u32 nwg = gx * gy * gz;
    u32 bx, by, bz;
    if ((nwg & 7u) == 0u) {
        u32 cpx = nwg >> 3;
        u32 nf = (flat & 7u) * cpx + (flat >> 3);
        bx = nf % gx; u32 t = nf / gx; by = t % gy; bz = t / gy;
    } else {
        bx = blockIdx.x; by = blockIdx.y; bz = blockIdx.z;
    }

    const long m0 = (long)by * BM, n0 = (long)bx * BN;

    const f16* pA = A + (size_t)bz * aBatch;
    const f16* pB = B + (size_t)bz * bBatch;

    int srow[2], scol[2];
#pragma unroll
    for (int i = 0; i < 2; i++) {
        int lin = i * 4096 + tid * 16;
        srow[i] = lin >> 6;            // row 0..127 (64B per row)
        scol[i] = (lin & 63) >> 1;     // f16 index 0..31 within row
    }

    const int wr = wave >> 1, wc = wave & 1;
    const int lrow = lane & 15, kgrp = lane >> 4;
    const int ko = kgrp * 8;

    f32x4 acc[4][4] = {};

    auto stage = [&](int b, int kt) {
#pragma unroll
        for (int i = 0; i < 2; i++) {
            size_t ga = (size_t)(m0 + srow[i]) * K + (size_t)kt * BKT + scol[i];
            size_t gb = (size_t)(n0 + srow[i]) * K + (size_t)kt * BKT + scol[i];
            u32 lb = (u32)(b * (HALFU * 2) + i * 4096 + wave * 1024); // bytes
            gll16(pA + ga, (char*)lds + 0 * 8192 + lb);
            gll16(pB + gb, (char*)lds + 1 * 8192 + lb);
        }
    };

    auto compute = [&](int b) {
        const u16* B0 = lds + b * HALFU;
        f16x8 a[4], bb[4];
#pragma unroll
        for (int m = 0; m < 4; m++) {
            int r = wr * 64 + m * 16 + lrow;
            a[m] = *(const f16x8*)&B0[0 * TILEU + r * 32 + ko];
        }
#pragma unroll
        for (int n = 0; n < 4; n++) {
            int r = wc * 64 + n * 16 + lrow;
            bb[n] = *(const f16x8*)&B0[1 * TILEU + r * 32 + ko];
        }
#pragma unroll
        for (int m = 0; m < 4; m++)
#pragma unroll
            for (int n = 0; n < 4; n++)
                acc[m][n] = __builtin_amdgcn_mfma_f32_16x16x32_f16(a[m], bb[n], acc[m][n], 0, 0, 0);
    };

    const int ksteps = K / BKT;      // 8 or 16
    stage(0, 0);
    __syncthreads();
    int cur = 0;
    for (int kt = 0; kt < ksteps - 1; ++kt) {
        stage(cur ^ 1, kt + 1);       // issue next tile first (overlaps compute)
        compute(cur);
        __syncthreads();
        cur ^= 1;
    }
    compute(cur);
    __syncthreads();                  // LDS free for epilogue reuse

    // ---- epilogue ----
    if constexpr (OUTMODE == 2) {
        float* Cf = (float*)C1;
#pragma unroll
        for (int m = 0; m < 4; m++)
#pragma unroll
            for (int n = 0; n < 4; n++) {
                long col = n0 + wc * 64 + n * 16 + lrow;
#pragma unroll
                for (int j = 0; j < 4; j++) {
                    long row = m0 + wr * 64 + m * 16 + kgrp * 4 + j;
                    Cf[(size_t)bz * cBatch + (size_t)row * N + col] = acc[m][n][j];
                }
            }
    } else {
        u16* sh = (u16*)lds;
#pragma unroll
        for (int m = 0; m < 4; m++) {
#pragma unroll
            for (int n = 0; n < 4; n++) {
                int col_l = wc * 64 + n * 16 + lrow;
                float bv = 0.f;
                if constexpr (BIAS) bv = bias[bz * biasBatch + n0 + col_l];
#pragma unroll
                for (int j = 0; j < 4; j++) {
                    int row_l = wr * 64 + m * 16 + kgrp * 4 + j;
                    int sc = col_l ^ (((row_l >> 2) & 3) << 4);
                    float v = acc[m][n][j];
                    if constexpr (BIAS) v += bv;
                    if constexpr (RELU) v = fmaxf(v, 0.f);
                    union { f16 f; u16 u; } cv; cv.f = (f16)v;
                    sh[row_l * 128 + sc] = cv.u;
                }
            }
        }
        __syncthreads();
#pragma unroll
        for (int i = 0; i < 8; i++) {
            int idx = i * 256 + tid;
            int row_l = idx >> 4;            // 0..127
            int c8 = (idx & 15) << 3;        // col start (multiple of 8)
            int sc = c8 ^ (((row_l >> 2) & 3) << 4);
            size_t go = (size_t)bz * cBatch + (size_t)(m0 + row_l) * N + n0 + c8;
            *(f16x8*)&C1[go] = *(const f16x8*)&sh[row_l * 128 + sc];
        }
    }
}

// ---------------- softmax: dist = softmax(10*S/rowmax) ----------------
// exp(c*v - 10) = 2^(c2*v - 14.4269504) with c2 = 10*log2(e)/m  [v_exp_f32 = 2^x]
#define LOG2E_10 14.4269504f

// fp32 in-place variant (fallback)
__global__ __launch_bounds__(256) void softmax_rows(float* __restrict__ S) {
    const int tid = threadIdx.x;
    float* p = S + (size_t)blockIdx.x * 4096;
    float4 v[4];
    float lmax = -3.4e38f;
#pragma unroll
    for (int i = 0; i < 4; i++) {
        v[i] = ((float4*)p)[tid + 256 * i];
        lmax = fmaxf(lmax, fmaxf(fmaxf(v[i].x, v[i].y), fmaxf(v[i].z, v[i].w)));
    }
#pragma unroll
    for (int o = 32; o; o >>= 1) lmax = fmaxf(lmax, __shfl_xor(lmax, o));
    __shared__ float redm[4];
    __shared__ float reds[4];
    if ((tid & 63) == 0) redm[tid >> 6] = lmax;
    __syncthreads();
    const float m = fmaxf(fmaxf(redm[0], redm[1]), fmaxf(redm[2], redm[3]));
    const float c2 = LOG2E_10 / m;
    float s = 0.f;
#pragma unroll
    for (int i = 0; i < 4; i++) {
        v[i].x = fexp2(c2 * v[i].x - LOG2E_10);
        v[i].y = fexp2(c2 * v[i].y - LOG2E_10);
        v[i].z = fexp2(c2 * v[i].z - LOG2E_10);
        v[i].w = fexp2(c2 * v[i].w - LOG2E_10);
        s += v[i].x + v[i].y + v[i].z + v[i].w;
    }
#pragma unroll
    for (int o = 32; o; o >>= 1) s += __shfl_xor(s, o);
    if ((tid & 63) == 0) reds[tid >> 6] = s;
    __syncthreads();
    const float inv = 1.0f / (reds[0] + reds[1] + reds[2] + reds[3]);
#pragma unroll
    for (int i = 0; i < 4; i++) {
        v[i].x *= inv; v[i].y *= inv; v[i].z *= inv; v[i].w *= inv;
        ((float4*)p)[tid + 256 * i] = v[i];
    }
}

// fp16-S variant: read fp16 S from ws, write fp32 dist to d_out
__global__ __launch_bounds__(256) void softmax_f16(const f16* __restrict__ S,
                                                   float* __restrict__ O) {
    const int tid = threadIdx.x;
    const f16* p = S + (size_t)blockIdx.x * 4096;
    float* o = O + (size_t)blockIdx.x * 4096;
    f16x8 a0 = ((const f16x8*)p)[tid];          // elements 8*tid ..
    f16x8 a1 = ((const f16x8*)p)[tid + 256];    // elements 8*(tid+256) ..
    float v[16];
#pragma unroll
    for (int j = 0; j < 8; j++) { v[j] = (float)a0[j]; v[8 + j] = (float)a1[j]; }
    float lmax = -3.4e38f;
#pragma unroll
    for (int j = 0; j < 16; j++) lmax = fmaxf(lmax, v[j]);
#pragma unroll
    for (int off = 32; off; off >>= 1) lmax = fmaxf(lmax, __shfl_xor(lmax, off));
    __shared__ float redm[4];
    __shared__ float reds[4];
    if ((tid & 63) == 0) redm[tid >> 6] = lmax;
    __syncthreads();
    const float m = fmaxf(fmaxf(redm[0], redm[1]), fmaxf(redm[2], redm[3]));
    const float c2 = LOG2E_10 / m;
    float s = 0.f;
#pragma unroll
    for (int j = 0; j < 16; j++) { v[j] = fexp2(c2 * v[j] - LOG2E_10); s += v[j]; }
#pragma unroll
    for (int off = 32; off; off >>= 1) s += __shfl_xor(s, off);
    if ((tid & 63) == 0) reds[tid >> 6] = s;
    __syncthreads();
    const float inv = 1.0f / (reds[0] + reds[1] + reds[2] + reds[3]);
    float4 w;
#pragma unroll
    for (int q = 0; q < 4; q++) {
        int base = q * 4;
        w.x = v[base + 0] * inv; w.y = v[base + 1] * inv;
        w.z = v[base + 2] * inv; w.w = v[base + 3] * inv;
        int idx = (q < 2) ? (2 * tid + q) : (2 * tid + 512 + (q - 2));
        ((float4*)o)[idx] = w;
    }
}

// ---------------- launch ----------------
extern "C" void kernel_launch(void* const* d_in, const int* in_sizes, int n_in,
                              void* d_out, int out_size, void* d_ws, size_t ws_size,
                              hipStream_t stream) {
    const float* x   = (const float*)d_in[0];
    const float* Wq1 = (const float*)d_in[1];
    const float* bq1 = (const float*)d_in[2];
    const float* Wq2 = (const float*)d_in[3];
    const float* bq2 = (const float*)d_in[4];
    const float* Wk1 = (const float*)d_in[5];
    const float* bk1 = (const float*)d_in[6];
    const float* Wk2 = (const float*)d_in[7];
    const float* bk2 = (const float*)d_in[8];
    float* out = (float*)d_out;

    const size_t MB = 1048576;
    char* ws = (char*)d_ws;
    // ws layout: biases | weights fp16 | Q/K fp16 | [S fp16 @ 20MB]
    float* b1 = (float*)(ws);                    // 4KB
    float* b2 = (float*)(ws + 4096);             // 2KB (reserve to 8KB)
    f16* w1f  = (f16*)(ws + 8 * 1024);           // 512KB  [2][512][256]
    f16* w2f  = (f16*)(ws + 8 * 1024 + 512 * 1024); // 512KB [2][256][512]
    f16* qf   = (f16*)(ws + 4 * MB);             // 8MB fp16 Q [4][4096][256]
    f16* kf   = (f16*)(ws + 12 * MB);            // 8MB fp16 K (contig after Q)
    f16* S16  = (f16*)(ws + 20 * MB);            // 128MB (needs ws >= 148MB)

    const bool f16s = (ws_size >= 149 * MB);

    // d_out doubles as scratch before QK^T/softmax overwrites it:
    char* ob = (char*)d_out;
    f16* xf = (f16*)(ob + 0 * MB);     // 8MB
    f16* Hf = (f16*)(ob + 16 * MB);    // [2][16384][512] fp16 = 32MB

    cast_x_kernel<<<4096, 256, 0, stream>>>(x, xf);
    cast_wT_kernel<<<dim3(512, 4), 256, 0, stream>>>(Wq1, Wk1, Wq2, Wk2, w1f, w2f);
    pack_bias<<<1, 512, 0, stream>>>(bq1, bk1, bq2, bk2, b1, b2);

    // layer 1 (both branches): H = relu(x*W1 + b1), fp16 out
    gemm_bt<1, 1, 1><<<dim3(4, 128, 2), 256, 0, stream>>>(
        xf, w1f, b1, 512,
        (u16*)Hf,
        16384, 512, 256,
        0L, 131072L, 8388608L);

    // layer 2 (both branches): Q/K = H*W2 + b2, fp16 out (Q then K in ws)
    gemm_bt<1, 0, 1><<<dim3(2, 128, 2), 256, 0, stream>>>(
        Hf, w2f, b2, 256,
        (u16*)qf,
        16384, 256, 512,
        8388608L, 131072L, 4194304L);

    // S = Q*K^T per batch: fp16 A,B, 1 MFMA
    if (f16s) {
        gemm_bt<0, 0, 1><<<dim3(32, 32, 4), 256, 0, stream>>>(
            qf, kf, nullptr, 0,
            (u16*)S16,
            4096, 4096, 256,
            1048576L, 1048576L, 16777216L);
        softmax_f16<<<16384, 256, 0, stream>>>(S16, out);
    } else {
        gemm_bt<0, 0, 2><<<dim3(32, 32, 4), 256, 0, stream>>>(
            qf, kf, nullptr, 0,
            (u16*)out,
            4096, 4096, 256,
            1048576L, 1048576L, 16777216L);
        softmax_rows<<<16384, 256, 0, stream>>>(out);
    }
}